// Round 3
// baseline (77.549 us; speedup 1.0000x reference)
//
#include <hip/hip_runtime.h>
#include <hip/hip_cooperative_groups.h>
#include <math.h>

namespace cg = cooperative_groups;

#define HH 512
#define WW 512
#define NN 10240
#define TILE 16
#define TXN 32              // tiles per row (512/16)
#define TYN 32
#define NT (TXN*TYN)        // 1024 tiles
#define CAP 256             // per-tile list capacity (mean ~25, max ~55 expected)
#define A_MIN (1.0f/255.0f)
#define A_MAX 0.999f

// One cooperative kernel: phase A (prep + scatter-bin) -> grid.sync -> phase B (render)
__global__ __launch_bounds__(256, 4) void fused_kernel(
    const float* __restrict__ xyz, const float* __restrict__ chol,
    const float* __restrict__ opac, const float* __restrict__ feat,
    float4* __restrict__ P0, float4* __restrict__ P1, float* __restrict__ P2b,
    int* __restrict__ counts, int* __restrict__ lists,
    float* __restrict__ out) {
  // ---------------- phase A: per-gaussian prep + binning ----------------
  int g = blockIdx.x * 256 + threadIdx.x;
  if (g < NN) {
    float mx = tanhf(xyz[2*g+0]);
    float my = tanhf(xyz[2*g+1]);
    float cx = 0.5f * WW * (mx + 1.0f);
    float cy = 0.5f * HH * (my + 1.0f);
    float l1 = chol[3*g+0] + 0.5f;
    float l2 = chol[3*g+1];
    float l3 = chol[3*g+2] + 0.5f;
    float c00 = l1*l1;
    float c01 = l1*l2;
    float c11 = l2*l2 + l3*l3;
    float det = c00*c11 - c01*c01;      // = l1^2 * l3^2 > 0 always
    float inv = 1.0f / det;
    float A = c11 * inv;
    float B = -c01 * inv;
    float C = c00 * inv;
    float op = opac[g];
    P0[g]  = make_float4(cx, cy, 0.5f * A, B);
    P1[g]  = make_float4(0.5f * C, op, feat[3*g+0], feat[3*g+1]);
    P2b[g] = feat[3*g+2];
    // support: alpha = op*exp(-sigma) >= 1/255  =>  sigma <= log(255*op)
    float smax = logf(op * 255.0f);
    if (smax > 0.0f) {
      float rx = sqrtf(2.0f * smax * c00) + 1.0f;   // +1 px margin
      float ry = sqrtf(2.0f * smax * c11) + 1.0f;
      int px0 = max(0,    (int)floorf(cx - rx));
      int px1 = min(WW-1, (int)floorf(cx + rx));
      int py0 = max(0,    (int)floorf(cy - ry));
      int py1 = min(HH-1, (int)floorf(cy + ry));
      if (px0 <= px1 && py0 <= py1) {
        int tx0 = px0 >> 4, tx1 = px1 >> 4;
        int ty0 = py0 >> 4, ty1 = py1 >> 4;
        for (int ty = ty0; ty <= ty1; ++ty)
          for (int tx = tx0; tx <= tx1; ++tx) {
            int t = ty * TXN + tx;
            int idx = atomicAdd(&counts[t], 1);
            if (idx < CAP) lists[t * CAP + idx] = g;
          }
      }
    }
  }

  cg::this_grid().sync();

  // ---------------- phase B: render own 16x16 tile ----------------
  __shared__ float4 sA[CAP];   // cx, cy, 0.5A, B
  __shared__ float4 sB[CAP];   // 0.5C, op, r, g
  __shared__ float  sC[CAP];   // blue

  int t  = blockIdx.x;
  int tx = t & (TXN - 1);
  int ty = t >> 5;
  int tid = threadIdx.x;

  int cnt = min(counts[t], CAP);
  if (tid < cnt) {
    int n = lists[t * CAP + tid];
    sA[tid] = P0[n];
    sB[tid] = P1[n];
    sC[tid] = P2b[n];
  }
  __syncthreads();

  int lx = tid & 15;
  int ly = tid >> 4;
  float px = tx * TILE + lx + 0.5f;
  float py = ty * TILE + ly + 0.5f;
  float accR = 0.0f, accG = 0.0f, accB = 0.0f;

  for (int j = 0; j < cnt; ++j) {
    float4 pa = sA[j];            // LDS broadcast — conflict-free
    float4 pb = sB[j];
    float dx = pa.x - px;
    float dy = pa.y - py;
    float sigma = pa.z * dx * dx + pb.x * dy * dy + pa.w * dy * dx;
    float alpha = fminf(A_MAX, pb.y * __expf(-sigma));
    if (sigma >= 0.0f && alpha >= A_MIN) {
      accR += alpha * pb.z;
      accG += alpha * pb.w;
      accB += alpha * sC[j];
    }
  }

  int x = tx * TILE + lx;
  int y = ty * TILE + ly;
  int pix = y * WW + x;
  out[0 * HH * WW + pix] = fminf(fmaxf(accR, 0.0f), 1.0f);
  out[1 * HH * WW + pix] = fminf(fmaxf(accG, 0.0f), 1.0f);
  out[2 * HH * WW + pix] = fminf(fmaxf(accB, 0.0f), 1.0f);
}

// ---------------- launcher ----------------
extern "C" void kernel_launch(void* const* d_in, const int* in_sizes, int n_in,
                              void* d_out, int out_size, void* d_ws, size_t ws_size,
                              hipStream_t stream) {
  const float* xyz  = (const float*)d_in[0];   // (N,2)
  const float* chol = (const float*)d_in[1];   // (N,3)
  const float* opac = (const float*)d_in[2];   // (N,1)
  const float* feat = (const float*)d_in[3];   // (N,3)
  float* out = (float*)d_out;

  char* ws = (char*)d_ws;
  float4* P0     = (float4*)(ws);                              // 163840 B
  float4* P1     = (float4*)(ws + (size_t)NN * 16);            // 163840 B
  float*  P2b    = (float*) (ws + (size_t)NN * 32);            //  40960 B
  int*    counts = (int*)   (ws + (size_t)NN * 36);            //   4096 B
  int*    lists  = (int*)   (ws + (size_t)NN * 36 + NT * 4);   //      1 MB

  hipMemsetAsync(counts, 0, NT * sizeof(int), stream);

  void* args[] = { (void*)&xyz, (void*)&chol, (void*)&opac, (void*)&feat,
                   (void*)&P0, (void*)&P1, (void*)&P2b,
                   (void*)&counts, (void*)&lists, (void*)&out };
  hipLaunchCooperativeKernel((const void*)fused_kernel,
                             dim3(NT), dim3(256), args, 0, stream);
}

// Round 4
// 22.034 us; speedup vs baseline: 3.5195x; 3.5195x over previous
//
#include <hip/hip_runtime.h>
#include <math.h>

#define HH 512
#define WW 512
#define NN 10240
#define TILE 16
#define TXN 32              // tiles per row (512/16)
#define TYN 32
#define CAP 256             // per-tile candidate capacity (mean ~25, max ~55 expected)
#define A_MIN (1.0f/255.0f)
#define A_MAX 0.999f

// ---------------- kernel 1: per-gaussian prep + exact tile-range pack -------
// P0 = (cx, cy, 0.5A, B)   P1 = (0.5C, op, r, g)   P2b = blue
// Qt = u32: tx0 | tx1<<8 | ty0<<16 | ty1<<24  (inclusive tile range; empty = 0xFF)
__global__ __launch_bounds__(256) void prep_kernel(
    const float* __restrict__ xyz, const float* __restrict__ chol,
    const float* __restrict__ opac, const float* __restrict__ feat,
    float4* __restrict__ P0, float4* __restrict__ P1,
    float* __restrict__ P2b, unsigned int* __restrict__ Qt) {
  int n = blockIdx.x * 256 + threadIdx.x;
  if (n >= NN) return;
  float mx = tanhf(xyz[2*n+0]);
  float my = tanhf(xyz[2*n+1]);
  float cx = 0.5f * WW * (mx + 1.0f);
  float cy = 0.5f * HH * (my + 1.0f);
  float l1 = chol[3*n+0] + 0.5f;
  float l2 = chol[3*n+1];
  float l3 = chol[3*n+2] + 0.5f;
  float c00 = l1*l1;
  float c01 = l1*l2;
  float c11 = l2*l2 + l3*l3;
  float det = c00*c11 - c01*c01;      // = l1^2 * l3^2 > 0 always
  float inv = 1.0f / det;
  float A = c11 * inv;
  float B = -c01 * inv;
  float C = c00 * inv;
  float op = opac[n];
  P0[n]  = make_float4(cx, cy, 0.5f * A, B);
  P1[n]  = make_float4(0.5f * C, op, feat[3*n+0], feat[3*n+1]);
  P2b[n] = feat[3*n+2];

  // support: alpha = op*exp(-sigma) >= 1/255  =>  sigma <= log(255*op)
  unsigned int q = 0x000000FFu;       // empty range (tx0=255 > tx1=0)
  float smax = logf(op * 255.0f);
  if (smax > 0.0f) {
    float rx = sqrtf(2.0f * smax * c00) + 1.0f;   // +1 px safety margin
    float ry = sqrtf(2.0f * smax * c11) + 1.0f;
    int px0 = max(0,    (int)floorf(cx - rx));
    int px1 = min(WW-1, (int)floorf(cx + rx));
    int py0 = max(0,    (int)floorf(cy - ry));
    int py1 = min(HH-1, (int)floorf(cy + ry));
    if (px0 <= px1 && py0 <= py1) {
      unsigned int tx0 = px0 >> 4, tx1 = px1 >> 4;
      unsigned int ty0 = py0 >> 4, ty1 = py1 >> 4;
      q = tx0 | (tx1 << 8) | (ty0 << 16) | (ty1 << 24);
    }
  }
  Qt[n] = q;
}

// ---------------- kernel 2: scan + render, one block per 16x16 tile ---------
__global__ __launch_bounds__(256, 4) void render_kernel(
    const float4* __restrict__ P0, const float4* __restrict__ P1,
    const float* __restrict__ P2b, const uint4* __restrict__ Q4,
    float* __restrict__ out) {
  __shared__ int    s_idx[CAP];
  __shared__ float4 sA[CAP];   // cx, cy, 0.5A, B
  __shared__ float4 sB[CAP];   // 0.5C, op, r, g
  __shared__ float  sC[CAP];   // blue
  __shared__ int    s_cnt;

  const int tx = blockIdx.x, ty = blockIdx.y;
  const int tid = threadIdx.x;
  if (tid == 0) s_cnt = 0;
  __syncthreads();

  // phase 1: integer scan of all N packed tile-ranges (coalesced uint4)
  #pragma unroll
  for (int i = 0; i < NN / (256 * 4); ++i) {
    uint4 q = Q4[i * 256 + tid];
    int base = (i * 256 + tid) * 4;
    unsigned int qq[4] = { q.x, q.y, q.z, q.w };
    #pragma unroll
    for (int s = 0; s < 4; ++s) {
      unsigned int v = qq[s];
      int tx0 = v & 0xFF, tx1 = (v >> 8) & 0xFF;
      int ty0 = (v >> 16) & 0xFF, ty1 = v >> 24;
      if (tx >= tx0 && tx <= tx1 && ty >= ty0 && ty <= ty1) {
        int k = atomicAdd(&s_cnt, 1);
        if (k < CAP) s_idx[k] = base + s;
      }
    }
  }
  __syncthreads();
  int cnt = min(s_cnt, CAP);

  // phase 2: gather params for the short list
  if (tid < cnt) {
    int n = s_idx[tid];
    sA[tid] = P0[n];
    sB[tid] = P1[n];
    sC[tid] = P2b[n];
  }
  __syncthreads();

  // phase 3: render one pixel per thread
  const int lx = tid & 15;
  const int ly = tid >> 4;
  const float px = tx * TILE + lx + 0.5f;
  const float py = ty * TILE + ly + 0.5f;
  float accR = 0.0f, accG = 0.0f, accB = 0.0f;

  for (int j = 0; j < cnt; ++j) {
    float4 pa = sA[j];            // LDS broadcast — conflict-free
    float4 pb = sB[j];
    float dx = pa.x - px;
    float dy = pa.y - py;
    float sigma = pa.z * dx * dx + pb.x * dy * dy + pa.w * dy * dx;
    float alpha = fminf(A_MAX, pb.y * __expf(-sigma));
    if (sigma >= 0.0f && alpha >= A_MIN) {
      accR += alpha * pb.z;
      accG += alpha * pb.w;
      accB += alpha * sC[j];
    }
  }

  const int x = tx * TILE + lx;
  const int y = ty * TILE + ly;
  const int pix = y * WW + x;
  out[0 * HH * WW + pix] = fminf(fmaxf(accR, 0.0f), 1.0f);
  out[1 * HH * WW + pix] = fminf(fmaxf(accG, 0.0f), 1.0f);
  out[2 * HH * WW + pix] = fminf(fmaxf(accB, 0.0f), 1.0f);
}

// ---------------- launcher ----------------
extern "C" void kernel_launch(void* const* d_in, const int* in_sizes, int n_in,
                              void* d_out, int out_size, void* d_ws, size_t ws_size,
                              hipStream_t stream) {
  const float* xyz  = (const float*)d_in[0];   // (N,2)
  const float* chol = (const float*)d_in[1];   // (N,3)
  const float* opac = (const float*)d_in[2];   // (N,1)
  const float* feat = (const float*)d_in[3];   // (N,3)

  char* ws = (char*)d_ws;
  float4*       P0  = (float4*)(ws);                    // 163840 B
  float4*       P1  = (float4*)(ws + (size_t)NN * 16);  // 163840 B
  float*        P2b = (float*) (ws + (size_t)NN * 32);  //  40960 B
  unsigned int* Qt  = (unsigned int*)(ws + (size_t)NN * 36);  // 40960 B

  prep_kernel<<<(NN + 255) / 256, 256, 0, stream>>>(xyz, chol, opac, feat, P0, P1, P2b, Qt);
  render_kernel<<<dim3(TXN, TYN), 256, 0, stream>>>(P0, P1, P2b, (const uint4*)Qt, (float*)d_out);
}

// Round 5
// 22.000 us; speedup vs baseline: 3.5249x; 1.0015x over previous
//
#include <hip/hip_runtime.h>
#include <math.h>

#define HH 512
#define WW 512
#define NN 10240
#define A_MIN (1.0f/255.0f)
#define A_MAX 0.999f

#define RB 16               // 16x16 regions of 32x32 px
#define WAVES 16
#define WRANGE (NN/WAVES)   // 640 gaussians per wave
#define WCHUNKS (WRANGE/64) // 10
#define RCAP 24             // per-wave region segment capacity (lambda ~4)
#define RSLOTS (WAVES*RCAP) // 384
#define PCAP 128            // per-tile param capacity (lambda ~24)

// ---------------- kernel 1: per-gaussian prep + exact tile-range pack -------
// P0 = (cx, cy, 0.5A, B)   P1 = (0.5C, op, r, g)   P2b = blue
// Qt = u32: tx0 | tx1<<8 | ty0<<16 | ty1<<24  (inclusive tile range; empty = 0xFF)
__global__ __launch_bounds__(256) void prep_kernel(
    const float* __restrict__ xyz, const float* __restrict__ chol,
    const float* __restrict__ opac, const float* __restrict__ feat,
    float4* __restrict__ P0, float4* __restrict__ P1,
    float* __restrict__ P2b, unsigned int* __restrict__ Qt) {
  int n = blockIdx.x * 256 + threadIdx.x;
  if (n >= NN) return;
  float mx = tanhf(xyz[2*n+0]);
  float my = tanhf(xyz[2*n+1]);
  float cx = 0.5f * WW * (mx + 1.0f);
  float cy = 0.5f * HH * (my + 1.0f);
  float l1 = chol[3*n+0] + 0.5f;
  float l2 = chol[3*n+1];
  float l3 = chol[3*n+2] + 0.5f;
  float c00 = l1*l1;
  float c01 = l1*l2;
  float c11 = l2*l2 + l3*l3;
  float det = c00*c11 - c01*c01;      // = l1^2 * l3^2 > 0 always
  float inv = 1.0f / det;
  float A = c11 * inv;
  float B = -c01 * inv;
  float C = c00 * inv;
  float op = opac[n];
  P0[n]  = make_float4(cx, cy, 0.5f * A, B);
  P1[n]  = make_float4(0.5f * C, op, feat[3*n+0], feat[3*n+1]);
  P2b[n] = feat[3*n+2];

  // support: alpha = op*exp(-sigma) >= 1/255  =>  sigma <= log(255*op)
  unsigned int q = 0x000000FFu;       // empty range (tx0=255 > tx1=0)
  float smax = logf(op * 255.0f);
  if (smax > 0.0f) {
    float rx = sqrtf(2.0f * smax * c00) + 1.0f;   // +1 px safety margin
    float ry = sqrtf(2.0f * smax * c11) + 1.0f;
    int px0 = max(0,    (int)floorf(cx - rx));
    int px1 = min(WW-1, (int)floorf(cx + rx));
    int py0 = max(0,    (int)floorf(cy - ry));
    int py1 = min(HH-1, (int)floorf(cy + ry));
    if (px0 <= px1 && py0 <= py1) {
      unsigned int tx0 = px0 >> 4, tx1 = px1 >> 4;
      unsigned int ty0 = py0 >> 4, ty1 = py1 >> 4;
      q = tx0 | (tx1 << 8) | (ty0 << 16) | (ty1 << 24);
    }
  }
  Qt[n] = q;
}

// ---------------- kernel 2: hierarchical scan + render ----------------------
// 256 blocks (16x16 regions of 32x32 px), 1024 threads. No atomics anywhere.
__global__ __launch_bounds__(1024, 4) void render_kernel(
    const float4* __restrict__ P0, const float4* __restrict__ P1,
    const float* __restrict__ P2b, const unsigned int* __restrict__ Qt,
    float* __restrict__ out)
{
  __shared__ uint2          reg2[RSLOTS];   // (Qt word, gaussian idx)
  __shared__ int            rcnt[WAVES];
  __shared__ unsigned short qseg[4][PCAP];
  __shared__ int            qcnt[4];
  __shared__ float4         pA[4][PCAP];    // cx, cy, 0.5A, B
  __shared__ float4         pB[4][PCAP];    // 0.5C, op, r, g
  __shared__ float          pC[4][PCAP];    // blue

  const int tid  = threadIdx.x;
  const int bx   = blockIdx.x, by = blockIdx.y;
  const int w    = tid >> 6;
  const int lane = tid & 63;

  // ---- phase 1: region-level scan, each gaussian tested ONCE per block ----
  {
    const int tx0r = 2*bx, tx1r = 2*bx + 1;
    const int ty0r = 2*by, ty1r = 2*by + 1;
    int base = 0;
    for (int c = 0; c < WCHUNKS; ++c) {
      int n = w*WRANGE + c*64 + lane;
      unsigned int v = Qt[n];
      int gtx0 = v & 0xFF, gtx1 = (v >> 8) & 0xFF;
      int gty0 = (v >> 16) & 0xFF, gty1 = v >> 24;
      bool hit = (gtx0 <= tx1r) & (gtx1 >= tx0r) & (gty0 <= ty1r) & (gty1 >= ty0r);
      unsigned long long m = __ballot(hit);
      int idx = base + (int)__popcll(m & ((1ull << lane) - 1ull));
      if (hit && idx < RCAP) reg2[w*RCAP + idx] = make_uint2(v, (unsigned)n);
      base += (int)__popcll(m);
      if (base >= RCAP) { base = RCAP; break; }   // wave-uniform
    }
    if (lane == 0) rcnt[w] = base;
  }
  __syncthreads();

  // ---- phase 2: refine region list into per-tile lists (waves 0..3) ----
  if (w < 4) {
    const int q   = w;
    const int ttx = 2*bx + (q & 1);
    const int tty = 2*by + (q >> 1);
    int base = 0;
    for (int c = 0; c < RSLOTS/64; ++c) {     // 6 chunks, slot order = index order
      int slot = c*64 + lane;
      int rr = slot / RCAP;
      int j  = slot - rr*RCAP;
      bool valid = j < rcnt[rr];
      unsigned int v = 0x000000FFu, n = 0;
      if (valid) { uint2 e = reg2[slot]; v = e.x; n = e.y; }
      int gtx0 = v & 0xFF, gtx1 = (v >> 8) & 0xFF;
      int gty0 = (v >> 16) & 0xFF, gty1 = v >> 24;
      bool hit = valid & (gtx0 <= ttx) & (gtx1 >= ttx) & (gty0 <= tty) & (gty1 >= tty);
      unsigned long long m = __ballot(hit);
      int idx = base + (int)__popcll(m & ((1ull << lane) - 1ull));
      if (hit && idx < PCAP) qseg[q][idx] = (unsigned short)n;
      base += (int)__popcll(m);
    }
    if (lane == 0) qcnt[q] = min(base, PCAP);
  }
  __syncthreads();

  // ---- phase 3: gather params for the short lists ----
  {
    int q = tid >> 8;
    int s = tid & 255;
    if (s < qcnt[q]) {
      int n = qseg[q][s];
      pA[q][s] = P0[n];
      pB[q][s] = P1[n];
      pC[q][s] = P2b[n];
    }
  }
  __syncthreads();

  // ---- phase 4: render one pixel per thread ----
  {
    int q = tid >> 8;                 // wave-uniform (256 | 64)
    int s = tid & 255;
    int lx = s & 15, ly = s >> 4;
    int x = bx*32 + (q & 1)*16 + lx;
    int y = by*32 + (q >> 1)*16 + ly;
    float px = x + 0.5f, py = y + 0.5f;
    int tot = qcnt[q];
    float accR = 0.0f, accG = 0.0f, accB = 0.0f;
    for (int j = 0; j < tot; ++j) {
      float4 pa = pA[q][j];           // LDS broadcast — conflict-free
      float4 pb = pB[q][j];
      float dx = pa.x - px;
      float dy = pa.y - py;
      float sigma = pa.z*dx*dx + pb.x*dy*dy + pa.w*dy*dx;
      float alpha = fminf(A_MAX, pb.y * __expf(-sigma));
      if (sigma >= 0.0f && alpha >= A_MIN) {
        accR += alpha * pb.z;
        accG += alpha * pb.w;
        accB += alpha * pC[q][j];
      }
    }
    int pix = y * WW + x;
    out[pix]              = fminf(fmaxf(accR, 0.0f), 1.0f);
    out[HH*WW + pix]      = fminf(fmaxf(accG, 0.0f), 1.0f);
    out[2*HH*WW + pix]    = fminf(fmaxf(accB, 0.0f), 1.0f);
  }
}

// ---------------- launcher ----------------
extern "C" void kernel_launch(void* const* d_in, const int* in_sizes, int n_in,
                              void* d_out, int out_size, void* d_ws, size_t ws_size,
                              hipStream_t stream) {
  const float* xyz  = (const float*)d_in[0];   // (N,2)
  const float* chol = (const float*)d_in[1];   // (N,3)
  const float* opac = (const float*)d_in[2];   // (N,1)
  const float* feat = (const float*)d_in[3];   // (N,3)

  char* ws = (char*)d_ws;
  float4*       P0  = (float4*)(ws);                          // 163840 B
  float4*       P1  = (float4*)(ws + (size_t)NN * 16);        // 163840 B
  float*        P2b = (float*) (ws + (size_t)NN * 32);        //  40960 B
  unsigned int* Qt  = (unsigned int*)(ws + (size_t)NN * 36);  //  40960 B

  prep_kernel<<<(NN + 255) / 256, 256, 0, stream>>>(xyz, chol, opac, feat, P0, P1, P2b, Qt);
  render_kernel<<<dim3(RB, RB), 1024, 0, stream>>>(P0, P1, P2b, Qt, (float*)d_out);
}

// Round 6
// 19.754 us; speedup vs baseline: 3.9258x; 1.1137x over previous
//
#include <hip/hip_runtime.h>
#include <math.h>

#define HH 512
#define WW 512
#define NN 10240
#define A_MIN (1.0f/255.0f)
#define A_MAX 0.999f

#define RB 16               // 16x16 blocks, each owns a 32x32-px region (4 tiles)
#define WAVES 16
#define WRANGE (NN/WAVES)   // 640 gaussians per wave
#define WCHUNKS (WRANGE/64) // 10
#define RCAP 24             // per-wave region segment capacity (lambda ~4.6)
#define RSLOTS (WAVES*RCAP) // 384
#define PCAP 128            // per-tile list capacity (lambda ~28)
#define SMAX_UB 5.5452f     // log(255) + eps  (op <= 1  =>  smax <= log 255)

// Single fused kernel: conservative discovery on raw inputs -> exact prep for
// candidates only -> per-tile refine -> render. One graph node, no atomics,
// no grid sync, fully deterministic.
__global__ __launch_bounds__(1024) void fused_kernel(
    const float* __restrict__ xyz, const float* __restrict__ chol,
    const float* __restrict__ opac, const float* __restrict__ feat,
    float* __restrict__ out)
{
  __shared__ int          ridx[RSLOTS];   // candidate gaussian index
  __shared__ int          rcnt[WAVES];
  __shared__ float4       pA[RSLOTS];     // cx, cy, 0.5A, B   (exact)
  __shared__ float4       pB[RSLOTS];     // 0.5C, op, r, g    (exact)
  __shared__ float        pC[RSLOTS];     // blue
  __shared__ unsigned int qw[RSLOTS];     // exact packed tile range
  __shared__ short        qseg[4][PCAP];  // per-tile slot lists
  __shared__ int          qcnt[4];

  const int tid  = threadIdx.x;
  const int bx   = blockIdx.x, by = blockIdx.y;
  const int w    = tid >> 6;
  const int lane = tid & 63;

  // ---- phase 1: conservative region-level scan of RAW inputs --------------
  // hit if the exact bbox [cx - rx - 1, cx + rx + 1] (rx = sqrt(2*smax*c00))
  // can overlap region pixels [32bx, 32bx+32). Squared-gap test, no sqrt/log.
  {
    const float rx0 = 32.f * bx,  rx1 = 32.f * bx + 32.f;
    const float ry0 = 32.f * by,  ry1 = 32.f * by + 32.f;
    int base = 0;
    for (int c = 0; c < WCHUNKS; ++c) {
      int n = w * WRANGE + c * 64 + lane;
      float2 xy = ((const float2*)xyz)[n];
      float l1 = chol[3*n+0] + 0.5f;
      float l2 = chol[3*n+1];
      float l3 = chol[3*n+2] + 0.5f;
      float c00 = l1*l1;
      float c11 = l2*l2 + l3*l3;
      // fast conservative tanh -> center (error ~1e-3 px, covered by pad)
      float ex = __expf(2.f * xy.x);
      float ey = __expf(2.f * xy.y);
      float cx = 256.f * (2.f - __fdividef(2.f, ex + 1.f));  // 256*(tanh+1)
      float cy = 256.f * (2.f - __fdividef(2.f, ey + 1.f));
      float rx2 = 2.f * SMAX_UB * c00;   // (rx upper bound)^2
      float ry2 = 2.f * SMAX_UB * c11;
      // gap beyond the +1px margin and +0.1 approx pad
      float gx = fmaxf(fmaxf(rx0 - cx, cx - rx1), 0.f) - 1.1f;
      float gy = fmaxf(fmaxf(ry0 - cy, cy - ry1), 0.f) - 1.1f;
      gx = fmaxf(gx, 0.f);
      gy = fmaxf(gy, 0.f);
      bool hit = (gx * gx <= rx2) & (gy * gy <= ry2);
      unsigned long long m = __ballot(hit);
      int idx = base + (int)__popcll(m & ((1ull << lane) - 1ull));
      if (hit && idx < RCAP) ridx[w * RCAP + idx] = n;
      base += (int)__popcll(m);
      if (base >= RCAP) { base = RCAP; break; }   // wave-uniform
    }
    if (lane == 0) rcnt[w] = base;
  }
  __syncthreads();

  // ---- phase 2: EXACT prep for candidates only (reference-identical) ------
  if (tid < RSLOTS) {
    int rr = tid / RCAP;
    int j  = tid - rr * RCAP;
    unsigned int q = 0x000000FFu;        // empty
    if (j < rcnt[rr]) {
      int n = ridx[tid];
      float mx = tanhf(xyz[2*n+0]);
      float my = tanhf(xyz[2*n+1]);
      float cx = 0.5f * WW * (mx + 1.0f);
      float cy = 0.5f * HH * (my + 1.0f);
      float l1 = chol[3*n+0] + 0.5f;
      float l2 = chol[3*n+1];
      float l3 = chol[3*n+2] + 0.5f;
      float c00 = l1*l1;
      float c01 = l1*l2;
      float c11 = l2*l2 + l3*l3;
      float det = c00*c11 - c01*c01;     // > 0 always
      float inv = 1.0f / det;
      float A = c11 * inv;
      float B = -c01 * inv;
      float C = c00 * inv;
      float op = opac[n];
      pA[tid] = make_float4(cx, cy, 0.5f * A, B);
      pB[tid] = make_float4(0.5f * C, op, feat[3*n+0], feat[3*n+1]);
      pC[tid] = feat[3*n+2];
      float smax = logf(op * 255.0f);
      if (smax > 0.0f) {
        float rx = sqrtf(2.0f * smax * c00) + 1.0f;
        float ry = sqrtf(2.0f * smax * c11) + 1.0f;
        int px0 = max(0,    (int)floorf(cx - rx));
        int px1 = min(WW-1, (int)floorf(cx + rx));
        int py0 = max(0,    (int)floorf(cy - ry));
        int py1 = min(HH-1, (int)floorf(cy + ry));
        if (px0 <= px1 && py0 <= py1) {
          unsigned int tx0 = px0 >> 4, tx1 = px1 >> 4;
          unsigned int ty0 = py0 >> 4, ty1 = py1 >> 4;
          q = tx0 | (tx1 << 8) | (ty0 << 16) | (ty1 << 24);
        }
      }
    }
    qw[tid] = q;
  }
  __syncthreads();

  // ---- phase 3: refine region slots into per-tile lists (waves 0..3) ------
  if (w < 4) {
    const int q   = w;
    const int ttx = 2*bx + (q & 1);
    const int tty = 2*by + (q >> 1);
    int base = 0;
    for (int c = 0; c < RSLOTS/64; ++c) {   // 6 chunks, slot order preserved
      int slot = c*64 + lane;
      unsigned int v = qw[slot];
      int tx0 = v & 0xFF, tx1 = (v >> 8) & 0xFF;
      int ty0 = (v >> 16) & 0xFF, ty1 = v >> 24;
      bool hit = (tx0 <= ttx) & (tx1 >= ttx) & (ty0 <= tty) & (ty1 >= tty);
      unsigned long long m = __ballot(hit);
      int idx = base + (int)__popcll(m & ((1ull << lane) - 1ull));
      if (hit && idx < PCAP) qseg[q][idx] = (short)slot;
      base += (int)__popcll(m);
    }
    if (lane == 0) qcnt[q] = min(base, PCAP);
  }
  __syncthreads();

  // ---- phase 4: render one pixel per thread --------------------------------
  {
    int q = tid >> 8;                 // wave-uniform
    int s = tid & 255;
    int lx = s & 15, ly = s >> 4;
    int x = bx*32 + (q & 1)*16 + lx;
    int y = by*32 + (q >> 1)*16 + ly;
    float px = x + 0.5f, py = y + 0.5f;
    int tot = qcnt[q];
    float accR = 0.0f, accG = 0.0f, accB = 0.0f;
    for (int j = 0; j < tot; ++j) {
      int slot = qseg[q][j];          // wave-uniform -> LDS broadcast
      float4 pa = pA[slot];
      float4 pb = pB[slot];
      float dx = pa.x - px;
      float dy = pa.y - py;
      float sigma = pa.z*dx*dx + pb.x*dy*dy + pa.w*dy*dx;
      float alpha = fminf(A_MAX, pb.y * __expf(-sigma));
      if (sigma >= 0.0f && alpha >= A_MIN) {
        accR += alpha * pb.z;
        accG += alpha * pb.w;
        accB += alpha * pC[slot];
      }
    }
    int pix = y * WW + x;
    out[pix]           = fminf(fmaxf(accR, 0.0f), 1.0f);
    out[HH*WW + pix]   = fminf(fmaxf(accG, 0.0f), 1.0f);
    out[2*HH*WW + pix] = fminf(fmaxf(accB, 0.0f), 1.0f);
  }
}

// ---------------- launcher: ONE kernel node ----------------
extern "C" void kernel_launch(void* const* d_in, const int* in_sizes, int n_in,
                              void* d_out, int out_size, void* d_ws, size_t ws_size,
                              hipStream_t stream) {
  const float* xyz  = (const float*)d_in[0];   // (N,2)
  const float* chol = (const float*)d_in[1];   // (N,3)
  const float* opac = (const float*)d_in[2];   // (N,1)
  const float* feat = (const float*)d_in[3];   // (N,3)

  fused_kernel<<<dim3(RB, RB), 1024, 0, stream>>>(xyz, chol, opac, feat, (float*)d_out);
}